// Round 2
// baseline (458.673 us; speedup 1.0000x reference)
//
#include <hip/hip_runtime.h>

#define LOG2E 1.44269504088896340736f

typedef _Float16 f16;
typedef __attribute__((ext_vector_type(8))) _Float16 f16x8;
typedef __attribute__((ext_vector_type(4))) float f32x4;
typedef __attribute__((ext_vector_type(8))) unsigned short us8;

#define BB 32
#define SSX 2048
#define SSY 2048
#define DD 160
#define M_TOTAL (BB*SSX)   // 65536

#define RS 168    // row stride for [rows][160] f16 LDS tiles (16B-aligned rows, conflict-light)
#define VT_RS 72  // Vt LDS row stride (64 y + 8 pad)
#define VO_RS 162 // proj V transpose buffer stride

__device__ __forceinline__ f32x4 mfma16(f16x8 a, f16x8 b, f32x4 c) {
  return __builtin_amdgcn_mfma_f32_16x16x32_f16(a, b, c, 0, 0, 0);
}

// ---- Projection kernel: Q = x Wq^T + bq ; K,V from y. V stored transposed. ----
// Split-fp16 precision: q = x_hi*W_hi + x_lo*W_hi + x_hi*W_lo  (lo*lo dropped)
__global__ __launch_bounds__(256) void proj_kernel(
    const float* __restrict__ x, const float* __restrict__ y,
    const float* __restrict__ Wq, const float* __restrict__ bq,
    const float* __restrict__ Wk, const float* __restrict__ bk,
    const float* __restrict__ Wv, const float* __restrict__ bv,
    f16* __restrict__ Qw, f16* __restrict__ Kw, f16* __restrict__ Vtw)
{
  __shared__ __align__(16) f16 buf[160*RS];   // 53.76 KB
  const int t = threadIdx.x;
  const int wave = t >> 6;
  const int lane = t & 63;
  const int quad = lane >> 4;
  const int l16  = lane & 15;
  const int bid  = blockIdx.x;
  const bool qpath = bid < 1024;
  const int tile = qpath ? bid : bid - 1024;
  const int row0 = tile * 64;
  const float* src = qpath ? x : y;

  // stage 64x160 input tile fp32 -> (hi, lo) fp16 pair; rows 0..63 = hi, 64..127 = lo
  for (int i = 0; i < 40; ++i) {
    int idx = t + i*256;
    int r = idx / 160, c = idx % 160;
    float v = src[(size_t)(row0 + r)*DD + c];
    f16 hi = (f16)v;
    buf[r*RS + c] = hi;
    buf[(64 + r)*RS + c] = (f16)(v - (float)hi);
  }
  __syncthreads();
  f16x8 a_hi[5], a_lo[5];
  #pragma unroll
  for (int ks = 0; ks < 5; ++ks) {
    a_hi[ks] = *(const f16x8*)&buf[(wave*16 + l16)*RS + ks*32 + quad*8];
    a_lo[ks] = *(const f16x8*)&buf[(64 + wave*16 + l16)*RS + ks*32 + quad*8];
  }
  __syncthreads();

  f32x4 acc[10];

  auto do_proj = [&](const float* W, const float* bias) {
    // pass 1: W_hi
    for (int i = 0; i < 100; ++i) {
      int idx = t + i*256;
      int r = idx / 160, c = idx % 160;
      buf[r*RS + c] = (f16)W[r*160 + c];
    }
    __syncthreads();
    #pragma unroll
    for (int nt = 0; nt < 10; ++nt) {
      float bs = bias[nt*16 + l16];
      acc[nt] = (f32x4){bs, bs, bs, bs};
      #pragma unroll
      for (int ks = 0; ks < 5; ++ks) {
        f16x8 bfr = *(const f16x8*)&buf[(nt*16 + l16)*RS + ks*32 + quad*8];
        acc[nt] = mfma16(a_hi[ks], bfr, acc[nt]);
        acc[nt] = mfma16(a_lo[ks], bfr, acc[nt]);
      }
    }
    __syncthreads();
    // pass 2: W_lo
    for (int i = 0; i < 100; ++i) {
      int idx = t + i*256;
      int r = idx / 160, c = idx % 160;
      float wv = W[r*160 + c];
      buf[r*RS + c] = (f16)(wv - (float)(f16)wv);
    }
    __syncthreads();
    #pragma unroll
    for (int nt = 0; nt < 10; ++nt)
      #pragma unroll
      for (int ks = 0; ks < 5; ++ks) {
        f16x8 bfr = *(const f16x8*)&buf[(nt*16 + l16)*RS + ks*32 + quad*8];
        acc[nt] = mfma16(a_hi[ks], bfr, acc[nt]);
      }
    __syncthreads(); // all waves done reading before buf reuse
  };

  if (qpath) {
    do_proj(Wq, bq);
    #pragma unroll
    for (int nt = 0; nt < 10; ++nt)
      #pragma unroll
      for (int r = 0; r < 4; ++r) {
        int row = row0 + wave*16 + quad*4 + r;
        Qw[(size_t)row*DD + nt*16 + l16] = (f16)acc[nt][r];
      }
  } else {
    do_proj(Wk, bk);
    #pragma unroll
    for (int nt = 0; nt < 10; ++nt)
      #pragma unroll
      for (int r = 0; r < 4; ++r) {
        int row = row0 + wave*16 + quad*4 + r;
        Kw[(size_t)row*DD + nt*16 + l16] = (f16)acc[nt][r];
      }
    do_proj(Wv, bv);
    // V tile -> LDS [y_local][d], then coalesced transposed global write
    #pragma unroll
    for (int nt = 0; nt < 10; ++nt)
      #pragma unroll
      for (int r = 0; r < 4; ++r)
        buf[(wave*16 + quad*4 + r)*VO_RS + nt*16 + l16] = (f16)acc[nt][r];
    __syncthreads();
    const int b  = row0 / SSY;
    const int y0 = row0 % SSY;
    for (int i = 0; i < 40; ++i) {
      int idx = t + i*256;          // lane = yy, wave+4i = d
      int d = idx >> 6, yy = idx & 63;
      Vtw[((size_t)b*DD + d)*SSY + y0 + yy] = buf[yy*VO_RS + d];
    }
  }
}

// ---------------- Flash attention + residual ----------------
__global__ __launch_bounds__(256) void flash_kernel(
    const f16* __restrict__ Qw, const f16* __restrict__ Kw, const f16* __restrict__ Vtw,
    const float* __restrict__ x, float* __restrict__ out)
{
  __shared__ __align__(16) f16 K_lds[64*RS];       // 21504 B (also Q staging)
  __shared__ __align__(16) f16 Vt_lds[160*VT_RS];  // 23040 B
  __shared__ __align__(16) f16 P_lds[4*16*VT_RS];  //  9216 B (per-wave 16x72)
  const int t = threadIdx.x;
  const int wave = t >> 6;
  const int lane = t & 63;
  const int quad = lane >> 4;
  const int l16  = lane & 15;
  const int bid  = blockIdx.x;
  const int b    = bid >> 5;
  const int x0   = (bid & 31) * 64;

  // stage Q tile (reuses K_lds), hoist A-frags
  {
    const f16* qsrc = Qw + ((size_t)b*SSX + x0)*DD;
    for (int i = 0; i < 5; ++i) {
      int idx = t + i*256;
      int r = idx / 20, c = idx % 20;
      *(us8*)&K_lds[r*RS + c*8] = *(const us8*)&qsrc[(size_t)r*DD + c*8];
    }
  }
  __syncthreads();
  f16x8 qfr[5];
  #pragma unroll
  for (int ks = 0; ks < 5; ++ks)
    qfr[ks] = *(const f16x8*)&K_lds[(wave*16 + l16)*RS + ks*32 + quad*8];

  f32x4 acc[10];
  #pragma unroll
  for (int i = 0; i < 10; ++i) acc[i] = (f32x4){0.f,0.f,0.f,0.f};
  float m_i[4], l_i[4];
  #pragma unroll
  for (int r = 0; r < 4; ++r) { m_i[r] = -1e30f; l_i[r] = 0.f; }

  f16* Pw = &P_lds[wave*16*VT_RS];

  for (int yc = 0; yc < SSY/64; ++yc) {
    const int ybase = yc*64;
    __syncthreads();  // previous iteration's reads done before restaging
    {
      const f16* ksrc = Kw + ((size_t)b*SSY + ybase)*DD;
      for (int i = 0; i < 5; ++i) {
        int idx = t + i*256;
        int r = idx / 20, c = idx % 20;
        *(us8*)&K_lds[r*RS + c*8] = *(const us8*)&ksrc[(size_t)r*DD + c*8];
      }
      const f16* vsrc = Vtw + (size_t)b*DD*SSY + ybase;
      for (int i = 0; i < 5; ++i) {
        int idx = t + i*256;
        int d = idx >> 3, c = idx & 7;
        *(us8*)&Vt_lds[d*VT_RS + c*8] = *(const us8*)&vsrc[(size_t)d*SSY + c*8];
      }
    }
    __syncthreads();

    // S = Q K^T  (16 q-rows x 64 y-cols per wave)
    f32x4 S[4];
    #pragma unroll
    for (int nt = 0; nt < 4; ++nt) {
      S[nt] = (f32x4){0.f,0.f,0.f,0.f};
      #pragma unroll
      for (int ks = 0; ks < 5; ++ks) {
        f16x8 kfr = *(const f16x8*)&K_lds[(nt*16 + l16)*RS + ks*32 + quad*8];
        S[nt] = mfma16(qfr[ks], kfr, S[nt]);
      }
    }

    // online softmax (rows m = quad*4+reg; cols across l16 and nt)
    float alpha[4];
    #pragma unroll
    for (int r = 0; r < 4; ++r) {
      float mx = fmaxf(fmaxf(S[0][r], S[1][r]), fmaxf(S[2][r], S[3][r]));
      #pragma unroll
      for (int off = 1; off < 16; off <<= 1) mx = fmaxf(mx, __shfl_xor(mx, off));
      float mn = fmaxf(m_i[r], mx);
      alpha[r] = exp2f((m_i[r] - mn)*LOG2E);
      m_i[r] = mn;
      float rs = 0.f;
      #pragma unroll
      for (int nt = 0; nt < 4; ++nt) {
        float p = exp2f((S[nt][r] - mn)*LOG2E);
        S[nt][r] = p;
        rs += p;
      }
      #pragma unroll
      for (int off = 1; off < 16; off <<= 1) rs += __shfl_xor(rs, off);
      l_i[r] = l_i[r]*alpha[r] + rs;
    }
    f32x4 av = {alpha[0], alpha[1], alpha[2], alpha[3]};
    #pragma unroll
    for (int i = 0; i < 10; ++i) acc[i] *= av;

    // P (C/D layout) -> LDS -> A-operand layout (per-wave region)
    #pragma unroll
    for (int nt = 0; nt < 4; ++nt)
      #pragma unroll
      for (int r = 0; r < 4; ++r)
        Pw[(quad*4 + r)*VT_RS + nt*16 + l16] = (f16)S[nt][r];

    #pragma unroll
    for (int k2 = 0; k2 < 2; ++k2) {
      f16x8 pfr = *(const f16x8*)&Pw[l16*VT_RS + k2*32 + quad*8];
      #pragma unroll
      for (int dt = 0; dt < 10; ++dt) {
        f16x8 vfr = *(const f16x8*)&Vt_lds[(dt*16 + l16)*VT_RS + k2*32 + quad*8];
        acc[dt] = mfma16(pfr, vfr, acc[dt]);
      }
    }
  }

  // epilogue: out = acc/l + x
  const size_t base = ((size_t)b*SSX + x0 + wave*16)*DD;
  float rl[4];
  #pragma unroll
  for (int r = 0; r < 4; ++r) rl[r] = 1.f/l_i[r];
  #pragma unroll
  for (int dt = 0; dt < 10; ++dt)
    #pragma unroll
    for (int r = 0; r < 4; ++r) {
      size_t o = base + (size_t)(quad*4 + r)*DD + dt*16 + l16;
      out[o] = acc[dt][r]*rl[r] + x[o];
    }
}

extern "C" void kernel_launch(void* const* d_in, const int* in_sizes, int n_in,
                              void* d_out, int out_size, void* d_ws, size_t ws_size,
                              hipStream_t stream) {
  const float* x  = (const float*)d_in[0];
  const float* y  = (const float*)d_in[1];
  const float* Wq = (const float*)d_in[2];
  const float* bq = (const float*)d_in[3];
  const float* Wk = (const float*)d_in[4];
  const float* bk = (const float*)d_in[5];
  const float* Wv = (const float*)d_in[6];
  const float* bv = (const float*)d_in[7];

  f16* Qw  = (f16*)d_ws;
  f16* Kw  = Qw + (size_t)M_TOTAL*DD;
  f16* Vtw = Kw + (size_t)M_TOTAL*DD;   // 63 MB of workspace total

  proj_kernel<<<2048, 256, 0, stream>>>(x, y, Wq, bq, Wk, bk, Wv, bv, Qw, Kw, Vtw);
  flash_kernel<<<1024, 256, 0, stream>>>(Qw, Kw, Vtw, x, (float*)d_out);
}